// Round 12
// baseline (46.201 us; speedup 1.0000x reference)
//
#include <hip/hip_runtime.h>

// attn [B=64, N=1024, N=1024] f32. Per (b, k=1..1022): unbiased std of the
// k-th super-diagonal scaled by (N-k)/5; mean over k then b -> scalar.
//
// R12: contiguous-band pass 1. Block (b,g) owns rows {16g..16g+15} and
// {1008-16g..1023-16g} (constant ~65.6KB/block, bands of consecutive rows
// are adjacent in memory -> near-sequential DRAM stream; tests the theory
// that R8's 262KB-strided walk capped pass 1 at ~4.3 TB/s).
// Per row i (band length L=1024-i, phase p=4-(r&3), L===p mod 4): thread t
// reads the aligned float4 at band position s=p+4t; quad valid iff s<L
// (all-or-nothing, single guard). Element j has diagonal offset k=s+j ->
// bin = k-4t-1 = p-1+j in 0..6, compile-time under full unroll.
// Bins resolved in LDS to plain [k]-indexed partials (k has <=2 (bin,thread)
// contributors: (b0=(k-1)&3, t0=(k-1)>>2) and (b0+4, t0-1) if b0<=2).
// Edge elements k=1..p-1 of each row: 48 lanes of wave 3, shfl reduce.
// Pass 2 (NB*16 blocks): sum 32 chunks at idx=k, std, block reduce.
// Pass 3: fixed-order final reduce. No atomics anywhere (R10: fused
// last-block epilogue cost +29us -> 3-kernel structure is mandatory).

#define NN 1024
#define NB 64
#define GPS 32          // chunks (blocks) per sample
#define WP 1032         // per-chunk section width (1024 k-slots + pad)
#define CW (2 * WP)     // chunk stride: [sum][sq]

__global__ __launch_bounds__(256) void diag_pass1(
    const float* __restrict__ attn, float* __restrict__ ws) {
  const int bid = blockIdx.x;
  const int b = bid >> 5;           // sample
  const int g = bid & 31;           // chunk in sample
  const int t = threadIdx.x;
  const int w = t >> 6;             // wave id

  const float* __restrict__ base = attn + ((size_t)b << 20);
  const int i0t = 16 * g;           // top rows: 0..511 over g
  const int i0b = 1008 - 16 * g;    // bottom rows: 512..1023 over g

  float bin1[7] = {0.f,0.f,0.f,0.f,0.f,0.f,0.f};
  float bin2[7] = {0.f,0.f,0.f,0.f,0.f,0.f,0.f};

  // Top half. Wave-uniform skip: wave w inactive if s>=L for all its rows.
  if (256 * w < 1024 - 16 * g) {
    #pragma unroll
    for (int r = 0; r < 16; ++r) {
      const int p = 4 - (r & 3);            // i0t%4==0 -> p == (-i) mod 4
      const int s = p + 4 * t;
      const int L = 1024 - (i0t + r);
      if (s < L) {                          // all-or-nothing (L===p mod 4)
        const float4 v = *reinterpret_cast<const float4*>(
            base + (size_t)(i0t + r) * (NN + 1) + s);
        bin1[p - 1] += v.x; bin2[p - 1] += v.x * v.x;
        bin1[p    ] += v.y; bin2[p    ] += v.y * v.y;
        bin1[p + 1] += v.z; bin2[p + 1] += v.z * v.z;
        bin1[p + 2] += v.w; bin2[p + 2] += v.w * v.w;
      }
    }
  }
  // Bottom half (L <= 16g+16).
  if (256 * w < 16 * g + 16) {
    #pragma unroll
    for (int r = 0; r < 16; ++r) {
      const int p = 4 - (r & 3);            // i0b%4==0 too
      const int s = p + 4 * t;
      const int L = 1024 - (i0b + r);
      if (s < L) {
        const float4 v = *reinterpret_cast<const float4*>(
            base + (size_t)(i0b + r) * (NN + 1) + s);
        bin1[p - 1] += v.x; bin2[p - 1] += v.x * v.x;
        bin1[p    ] += v.y; bin2[p    ] += v.y * v.y;
        bin1[p + 1] += v.z; bin2[p + 1] += v.z * v.z;
        bin1[p + 2] += v.w; bin2[p + 2] += v.w * v.w;
      }
    }
  }

  __shared__ float L1[7 * 256], L2[7 * 256];
  __shared__ float E1[4], E2[4];
  #pragma unroll
  for (int bq = 0; bq < 7; ++bq) {
    L1[bq * 256 + t] = bin1[bq];
    L2[bq * 256 + t] = bin2[bq];
  }

  // Edge elements k=1..p-1 per row (24 per 16-row half): wave 3, 48 lanes.
  if (w == 3) {
    const int l = t & 63;
    float x = 0.f; int e = 0;
    if (l < 48) {
      const int h = l / 24, m = l % 24;
      const int grp = m / 6, idx = m % 6;
      // per 4-row group: (dr,e) in {(0,1),(0,2),(0,3),(1,1),(1,2),(2,1)}
      const int dr = idx < 3 ? 0 : (idx < 5 ? 1 : 2);
      const int ee = idx < 3 ? idx + 1 : (idx < 5 ? idx - 2 : 1);
      const int i = (h ? i0b : i0t) + grp * 4 + dr;
      if (ee < 1024 - i) {                  // k=ee valid iff ee < L
        x = base[(size_t)i * (NN + 1) + ee];
        e = ee;
      }
    }
    const float xx = x * x;
    #pragma unroll
    for (int eb = 1; eb <= 3; ++eb) {
      float v1 = (e == eb) ? x : 0.f;
      float v2 = (e == eb) ? xx : 0.f;
      #pragma unroll
      for (int sft = 1; sft < 64; sft <<= 1) {
        v1 += __shfl_xor(v1, sft);
        v2 += __shfl_xor(v2, sft);
      }
      if (l == 0) { E1[eb] = v1; E2[eb] = v2; }
    }
  }
  __syncthreads();

  // Resolve bins -> plain k-indexed partials; coalesced stores.
  float* __restrict__ wout = ws + (size_t)bid * CW;
  #pragma unroll
  for (int j = 0; j < 4; ++j) {
    const int k = 1 + t + 256 * j;
    if (k <= 1023) {
      const int b0  = (k - 1) & 3;
      const int tt0 = (k - 1) >> 2;
      float s1 = L1[b0 * 256 + tt0];
      float s2 = L2[b0 * 256 + tt0];
      if (b0 <= 2 && tt0 >= 1) {            // second contributor (b0+4, tt0-1)
        s1 += L1[(b0 + 4) * 256 + tt0 - 1];
        s2 += L2[(b0 + 4) * 256 + tt0 - 1];
      }
      if (k <= 3) { s1 += E1[k]; s2 += E2[k]; }
      wout[k]      = s1;
      wout[WP + k] = s2;
    }
  }
}

// Block (b, kg): k = kg*64 + kk; cg = t>>6 sums chunks c = cg, cg+4, ...
__global__ __launch_bounds__(256) void diag_pass2(
    const float* __restrict__ ws, float* __restrict__ part) {
  const int b  = blockIdx.x >> 4;
  const int kg = blockIdx.x & 15;
  const int t  = threadIdx.x;
  const int kk = t & 63;
  const int cg = t >> 6;
  const int k  = kg * 64 + kk;       // 0..1023; valid 1..1022

  float s1 = 0.f, s2 = 0.f;
  #pragma unroll
  for (int c = cg; c < GPS; c += 4) {
    const float* __restrict__ w0 = ws + (size_t)(b * GPS + c) * CW;
    s1 += w0[k];
    s2 += w0[WP + k];
  }

  __shared__ float r1[256], r2[256];
  r1[t] = s1; r2[t] = s2;
  __syncthreads();
  if (t < 128) { r1[t] += r1[t + 128]; r2[t] += r2[t + 128]; }
  __syncthreads();
  if (t < 64) {
    s1 = r1[t] + r1[t + 64];
    s2 = r2[t] + r2[t + 64];
    float acc = 0.f;
    if (k >= 1 && k <= NN - 2) {
      const float n = (float)(NN - k);
      const float mean = s1 / n;
      const float var = fmaxf(s2 - n * mean * mean, 0.f) / (n - 1.f);
      acc = sqrtf(var) * (n * 0.2f);   // std * (N-k)/5
    }
    #pragma unroll
    for (int s = 32; s > 0; s >>= 1) acc += __shfl_down(acc, s);
    if (t == 0) part[blockIdx.x] = acc;
  }
}

__global__ __launch_bounds__(256) void diag_pass3(
    const float* __restrict__ part, float* __restrict__ out) {
  const int t = threadIdx.x;
  float v = part[t] + part[t + 256] + part[t + 512] + part[t + 768];
  __shared__ float red[256];
  red[t] = v;
  __syncthreads();
  #pragma unroll
  for (int s = 128; s > 0; s >>= 1) {
    if (t < s) red[t] += red[t + s];
    __syncthreads();
  }
  if (t == 0) out[0] = red[0] * (1.0f / (1022.0f * 64.0f));
}

extern "C" void kernel_launch(void* const* d_in, const int* in_sizes, int n_in,
                              void* d_out, int out_size, void* d_ws, size_t ws_size,
                              hipStream_t stream) {
  const float* attn = (const float*)d_in[0];
  float* out = (float*)d_out;
  float* ws = (float*)d_ws;

  float* part = ws + (size_t)NB * GPS * CW;   // 1024 f32 (after 16.9 MB)

  diag_pass1<<<NB * GPS, 256, 0, stream>>>(attn, ws);
  diag_pass2<<<NB * 16, 256, 0, stream>>>(ws, part);
  diag_pass3<<<1, 256, 0, stream>>>(part, out);
}

// Round 13
// 37.500 us; speedup vs baseline: 1.2320x; 1.2320x over previous
//
#include <hip/hip_runtime.h>

// attn [B=64, N=1024, N=1024] f32. Per (b, k=1..1022): unbiased std of the
// k-th super-diagonal scaled by (N-k)/5; mean over k then b -> scalar.
//
// R13 = R11 (champion, 40.45us) + ONE change: A/B quad partials folded in
// pass 1 via an 8KB LDS exchange (thread t's A-quad t + thread 255-t's
// B-quad t), halving ws traffic (16.9 -> 8.4 MB) and pass-2 work.
// Pass-1 hot loop byte-identical to R11. 3-kernel structure mandatory
// (R10: fused last-block epilogue +29us).
//
// Pass 1 (grid NB*RCH, 256 thr): complementary quad pairing. Thread t owns
// quad k0=p+4t (FIRST half of its valid rows) and quad 255-t (SECOND half
// of its rows); trip counts sum to ~64 -> all waves dense. Phase alignment
// makes every quad row-wise all-or-nothing valid -> no partial rows, all
// loads unconditional. Measured: diagonal-segment read pattern caps at
// ~4.3 TB/s regardless of structure (R2/R8/R12 bracket).
// ws per block: [sum][sq] x W; edges k=1..p-1 at slot 1024+k.
// Pass 2 (grid NB*16): sum chunks at idx (phase-relative), std, block
// reduce -> part[1024]. Pass 3 (1 block): fixed-order reduce -> scalar.

#define NN 1024
#define NB 64
#define RCH 16
#define W 1032   // section stride: 1024 slots + 3 edge + pad

__global__ __launch_bounds__(256) void diag_pass1(
    const float* __restrict__ attn, float* __restrict__ ws) {
  const int b = blockIdx.x >> 4;    // / RCH
  const int c = blockIdx.x & 15;    // % RCH
  const int t = threadIdx.x;
  int p = (4 - (c & 3)) & 3; if (p == 0) p = 4;   // k = p+4t is 16B-aligned

  const float* __restrict__ base = attn + ((size_t)b << 20);
  const float* __restrict__ rowc = base + (size_t)c * (NN + 1);
  const size_t stride = (size_t)RCH * (NN + 1);

  // Quad A = t: rows m in [0, SaA)  (first half of its valid range)
  const int k0a = p + 4 * t;
  const int dfA = 1020 - c - p - 4 * t;           // full-valid iff 16m <= dfA
  const int TfA = (dfA >= 0) ? ((dfA >> 4) + 1) : 0;
  const int SaA = (TfA + 1) >> 1;

  float a1x=0.f,a1y=0.f,a1z=0.f,a1w=0.f,a2x=0.f,a2y=0.f,a2z=0.f,a2w=0.f;
  {
    const float* ptr = rowc + k0a;
    #pragma unroll 8
    for (int m = 0; m < SaA; ++m) {
      const float4 v = *reinterpret_cast<const float4*>(ptr + (size_t)m * stride);
      a1x += v.x; a2x += v.x * v.x;
      a1y += v.y; a2y += v.y * v.y;
      a1z += v.z; a2z += v.z * v.z;
      a1w += v.w; a2w += v.w * v.w;
    }
  }

  // Quad B = 255-t: rows m in [SaB, TfB)  (second half of ITS valid range)
  const int qB  = 255 - t;
  const int k0b = p + 4 * qB;
  const int dfB = 4 * t - c - p;                  // = 1020-c-p-4*qB
  const int TfB = (dfB >= 0) ? ((dfB >> 4) + 1) : 0;
  const int SaB = (TfB + 1) >> 1;

  float b1x=0.f,b1y=0.f,b1z=0.f,b1w=0.f,b2x=0.f,b2y=0.f,b2z=0.f,b2w=0.f;
  {
    const float* ptr = rowc + k0b;
    #pragma unroll 8
    for (int m = SaB; m < TfB; ++m) {
      const float4 v = *reinterpret_cast<const float4*>(ptr + (size_t)m * stride);
      b1x += v.x; b2x += v.x * v.x;
      b1y += v.y; b2y += v.y * v.y;
      b1z += v.z; b2z += v.z * v.z;
      b1w += v.w; b2w += v.w * v.w;
    }
  }

  // Fold: LDS slot q holds B-partials of quad q (written by thread 255-q).
  __shared__ float4 lb1[256], lb2[256];
  lb1[qB] = make_float4(b1x, b1y, b1z, b1w);
  lb2[qB] = make_float4(b2x, b2y, b2z, b2w);
  __syncthreads();
  const float4 f1 = lb1[t];
  const float4 f2 = lb2[t];
  a1x += f1.x; a1y += f1.y; a1z += f1.z; a1w += f1.w;
  a2x += f2.x; a2y += f2.y; a2z += f2.z; a2w += f2.w;

  float* __restrict__ w1 = ws + (size_t)blockIdx.x * (2 * W);
  *reinterpret_cast<float4*>(w1 + 4 * t)     = make_float4(a1x,a1y,a1z,a1w);
  *reinterpret_cast<float4*>(w1 + W + 4 * t) = make_float4(a2x,a2y,a2z,a2w);

  // Edge columns k = 1..p-1: wave w==e, one row per lane + shfl reduce.
  const int e = t >> 6;
  if (e >= 1 && e < p) {
    const int l = t & 63;
    const int i = c + RCH * l;                    // NN/RCH = 64 rows exactly
    float x = 0.f;
    if (i + e < NN) x = base[(size_t)i * (NN + 1) + e];
    float e1 = x, e2 = x * x;
    #pragma unroll
    for (int s = 1; s < 64; s <<= 1) {
      e1 += __shfl_xor(e1, s);
      e2 += __shfl_xor(e2, s);
    }
    if (l == 0) {
      w1[1024 + e]     = e1;
      w1[W + 1024 + e] = e2;
    }
  }
}

// Block (b, kg): k = kg*64 + kk; cg = t>>6 sums chunks c = cg, cg+4, ...
__global__ __launch_bounds__(256) void diag_pass2(
    const float* __restrict__ ws, float* __restrict__ part) {
  const int b  = blockIdx.x >> 4;
  const int kg = blockIdx.x & 15;
  const int t  = threadIdx.x;
  const int kk = t & 63;
  const int cg = t >> 6;
  const int k  = kg * 64 + kk;

  int p = (4 - cg) & 3; if (p == 0) p = 4;        // phase for c = cg (mod 4)
  const int idx = (k >= p) ? (k - p) : (1024 + k);

  float s1 = 0.f, s2 = 0.f;
  #pragma unroll
  for (int c = cg; c < RCH; c += 4) {
    const float* __restrict__ w0 = ws + (size_t)(b * RCH + c) * (2 * W);
    s1 += w0[idx];
    s2 += w0[W + idx];
  }

  __shared__ float r1[256], r2[256];
  r1[t] = s1; r2[t] = s2;
  __syncthreads();
  if (t < 128) { r1[t] += r1[t + 128]; r2[t] += r2[t + 128]; }
  __syncthreads();
  if (t < 64) {
    s1 = r1[t] + r1[t + 64];
    s2 = r2[t] + r2[t + 64];
    float acc = 0.f;
    if (k >= 1 && k <= NN - 2) {
      const float n = (float)(NN - k);
      const float mean = s1 / n;
      const float var = fmaxf(s2 - n * mean * mean, 0.f) / (n - 1.f);
      acc = sqrtf(var) * (n * 0.2f);              // std * (N-k)/5
    }
    #pragma unroll
    for (int s = 32; s > 0; s >>= 1) acc += __shfl_down(acc, s);
    if (t == 0) part[blockIdx.x] = acc;
  }
}

__global__ __launch_bounds__(256) void diag_pass3(
    const float* __restrict__ part, float* __restrict__ out) {
  const int t = threadIdx.x;
  float v = part[t] + part[t + 256] + part[t + 512] + part[t + 768];
  __shared__ float red[256];
  red[t] = v;
  __syncthreads();
  #pragma unroll
  for (int s = 128; s > 0; s >>= 1) {
    if (t < s) red[t] += red[t + s];
    __syncthreads();
  }
  if (t == 0) out[0] = red[0] * (1.0f / (1022.0f * 64.0f));
}

extern "C" void kernel_launch(void* const* d_in, const int* in_sizes, int n_in,
                              void* d_out, int out_size, void* d_ws, size_t ws_size,
                              hipStream_t stream) {
  const float* attn = (const float*)d_in[0];
  float* out = (float*)d_out;
  float* ws = (float*)d_ws;

  float* part = ws + (size_t)NB * RCH * 2 * W;    // 1024 f32

  diag_pass1<<<NB * RCH, 256, 0, stream>>>(attn, ws);
  diag_pass2<<<NB * 16, 256, 0, stream>>>(ws, part);
  diag_pass3<<<1, 256, 0, stream>>>(part, out);
}

// Round 14
// 36.735 us; speedup vs baseline: 1.2577x; 1.0208x over previous
//
#include <hip/hip_runtime.h>

// attn [B=64, N=1024, N=1024] f32. Per (b, k=1..1022): unbiased std of the
// k-th super-diagonal scaled by (N-k)/5; mean over k then b -> scalar.
//
// R14 = R13 (champion, 37.5us) + ONE change: chunk-pairing. Chunks c and c+8
// share phase p (same slot mapping), so one block accumulates BOTH c-sets
// into the same registers before a single store. Grid 512 blocks; global
// read set and per-thread pattern shape identical to R13; ws halves again
// (8.4 -> 4.2 MB), pass-2 chunk loop 4 -> 2 iters. Tests the measured
// ~5.6 TB/s marginal cost of partial-traffic (R13's win).
//
// Pass 1 (grid NB*8, 256 thr): complementary quad pairing per c-set.
// Thread t owns quad k0=p+4t (FIRST half of its valid rows) and quad 255-t
// (SECOND half), for cc in {c0, c0+8}. Phase alignment -> no partial rows,
// all loads unconditional. Diagonal-segment read measured pattern-capped at
// ~4.3 TB/s (R2/R8/R12 bracket). ws per block: [sum][sq] x W; edges
// k=1..p-1 at slot 1024+k. 3-kernel structure mandatory (R10: +29us fused).
// Pass 2 (grid NB*16): sum 8 chunks at phase-relative idx, std, block
// reduce -> part[1024]. Pass 3 (1 block): fixed-order reduce -> scalar.

#define NN 1024
#define NB 64
#define W 1032   // section stride: 1024 slots + 3 edge + pad

__global__ __launch_bounds__(256) void diag_pass1(
    const float* __restrict__ attn, float* __restrict__ ws) {
  const int b  = blockIdx.x >> 3;   // sample
  const int c0 = blockIdx.x & 7;    // chunk pair: covers c0 and c0+8
  const int t  = threadIdx.x;
  int p = (4 - (c0 & 3)) & 3; if (p == 0) p = 4;  // k = p+4t is 16B-aligned

  const float* __restrict__ base = attn + ((size_t)b << 20);
  const size_t stride = (size_t)16 * (NN + 1);    // rows within a c-set

  const int qB = 255 - t;
  float a1x=0.f,a1y=0.f,a1z=0.f,a1w=0.f,a2x=0.f,a2y=0.f,a2z=0.f,a2w=0.f;
  float b1x=0.f,b1y=0.f,b1z=0.f,b1w=0.f,b2x=0.f,b2y=0.f,b2z=0.f,b2w=0.f;

  #pragma unroll
  for (int h = 0; h < 2; ++h) {
    const int c = c0 + 8 * h;
    const float* __restrict__ rowc = base + (size_t)c * (NN + 1);

    // Quad A = t: rows m in [0, SaA)  (first half of its valid range)
    const int dfA = 1020 - c - p - 4 * t;         // full-valid iff 16m <= dfA
    const int TfA = (dfA >= 0) ? ((dfA >> 4) + 1) : 0;
    const int SaA = (TfA + 1) >> 1;
    {
      const float* ptr = rowc + (p + 4 * t);
      #pragma unroll 8
      for (int m = 0; m < SaA; ++m) {
        const float4 v = *reinterpret_cast<const float4*>(ptr + (size_t)m * stride);
        a1x += v.x; a2x += v.x * v.x;
        a1y += v.y; a2y += v.y * v.y;
        a1z += v.z; a2z += v.z * v.z;
        a1w += v.w; a2w += v.w * v.w;
      }
    }

    // Quad B = 255-t: rows m in [SaB, TfB)  (second half of ITS range)
    const int dfB = 4 * t - c - p;                // = 1020-c-p-4*qB
    const int TfB = (dfB >= 0) ? ((dfB >> 4) + 1) : 0;
    const int SaB = (TfB + 1) >> 1;
    {
      const float* ptr = rowc + (p + 4 * qB);
      #pragma unroll 8
      for (int m = SaB; m < TfB; ++m) {
        const float4 v = *reinterpret_cast<const float4*>(ptr + (size_t)m * stride);
        b1x += v.x; b2x += v.x * v.x;
        b1y += v.y; b2y += v.y * v.y;
        b1z += v.z; b2z += v.z * v.z;
        b1w += v.w; b2w += v.w * v.w;
      }
    }
  }

  // Fold: LDS slot q holds B-partials of quad q (written by thread 255-q).
  __shared__ float4 lb1[256], lb2[256];
  lb1[qB] = make_float4(b1x, b1y, b1z, b1w);
  lb2[qB] = make_float4(b2x, b2y, b2z, b2w);
  __syncthreads();
  const float4 f1 = lb1[t];
  const float4 f2 = lb2[t];
  a1x += f1.x; a1y += f1.y; a1z += f1.z; a1w += f1.w;
  a2x += f2.x; a2y += f2.y; a2z += f2.z; a2w += f2.w;

  float* __restrict__ w1 = ws + (size_t)blockIdx.x * (2 * W);
  *reinterpret_cast<float4*>(w1 + 4 * t)     = make_float4(a1x,a1y,a1z,a1w);
  *reinterpret_cast<float4*>(w1 + W + 4 * t) = make_float4(a2x,a2y,a2z,a2w);

  // Edge columns k = 1..p-1: wave w==e, one row per lane, both c-sets.
  const int e = t >> 6;
  if (e >= 1 && e < p) {
    const int l = t & 63;
    float e1 = 0.f, e2 = 0.f;
    #pragma unroll
    for (int h = 0; h < 2; ++h) {
      const int i = c0 + 8 * h + 16 * l;          // 64 rows per c-set
      if (i + e < NN) {
        const float x = base[(size_t)i * (NN + 1) + e];
        e1 += x; e2 += x * x;
      }
    }
    #pragma unroll
    for (int s = 1; s < 64; s <<= 1) {
      e1 += __shfl_xor(e1, s);
      e2 += __shfl_xor(e2, s);
    }
    if (l == 0) {
      w1[1024 + e]     = e1;
      w1[W + 1024 + e] = e2;
    }
  }
}

// Block (b, kg): k = kg*64 + kk; cg = t>>6 sums chunks c = cg, cg+4.
__global__ __launch_bounds__(256) void diag_pass2(
    const float* __restrict__ ws, float* __restrict__ part) {
  const int b  = blockIdx.x >> 4;
  const int kg = blockIdx.x & 15;
  const int t  = threadIdx.x;
  const int kk = t & 63;
  const int cg = t >> 6;
  const int k  = kg * 64 + kk;

  int p = (4 - cg) & 3; if (p == 0) p = 4;        // phase for chunk c = cg mod 4
  const int idx = (k >= p) ? (k - p) : (1024 + k);

  float s1 = 0.f, s2 = 0.f;
  #pragma unroll
  for (int c = cg; c < 8; c += 4) {
    const float* __restrict__ w0 = ws + (size_t)(b * 8 + c) * (2 * W);
    s1 += w0[idx];
    s2 += w0[W + idx];
  }

  __shared__ float r1[256], r2[256];
  r1[t] = s1; r2[t] = s2;
  __syncthreads();
  if (t < 128) { r1[t] += r1[t + 128]; r2[t] += r2[t + 128]; }
  __syncthreads();
  if (t < 64) {
    s1 = r1[t] + r1[t + 64];
    s2 = r2[t] + r2[t + 64];
    float acc = 0.f;
    if (k >= 1 && k <= NN - 2) {
      const float n = (float)(NN - k);
      const float mean = s1 / n;
      const float var = fmaxf(s2 - n * mean * mean, 0.f) / (n - 1.f);
      acc = sqrtf(var) * (n * 0.2f);              // std * (N-k)/5
    }
    #pragma unroll
    for (int s = 32; s > 0; s >>= 1) acc += __shfl_down(acc, s);
    if (t == 0) part[blockIdx.x] = acc;
  }
}

__global__ __launch_bounds__(256) void diag_pass3(
    const float* __restrict__ part, float* __restrict__ out) {
  const int t = threadIdx.x;
  float v = part[t] + part[t + 256] + part[t + 512] + part[t + 768];
  __shared__ float red[256];
  red[t] = v;
  __syncthreads();
  #pragma unroll
  for (int s = 128; s > 0; s >>= 1) {
    if (t < s) red[t] += red[t + s];
    __syncthreads();
  }
  if (t == 0) out[0] = red[0] * (1.0f / (1022.0f * 64.0f));
}

extern "C" void kernel_launch(void* const* d_in, const int* in_sizes, int n_in,
                              void* d_out, int out_size, void* d_ws, size_t ws_size,
                              hipStream_t stream) {
  const float* attn = (const float*)d_in[0];
  float* out = (float*)d_out;
  float* ws = (float*)d_ws;

  float* part = ws + (size_t)NB * 8 * 2 * W;      // 1024 f32 (after 4.2 MB)

  diag_pass1<<<NB * 8, 256, 0, stream>>>(attn, ws);
  diag_pass2<<<NB * 16, 256, 0, stream>>>(ws, part);
  diag_pass3<<<1, 256, 0, stream>>>(part, out);
}